// Round 14
// baseline (434.216 us; speedup 1.0000x reference)
//
#include <hip/hip_runtime.h>
#include <hip/hip_bf16.h>

#define IN_C 128
#define HID_C 128
#define OUT_C 64

typedef unsigned short u16;
typedef unsigned int   u32;
typedef __attribute__((ext_vector_type(8))) short short8;
typedef __attribute__((ext_vector_type(4))) float f32x4;
typedef __attribute__((ext_vector_type(2))) float f32x2;

__device__ __forceinline__ u16 bf16_bits(float x) {
    __hip_bfloat16 h = __float2bfloat16(x);   // RNE
    return *(u16*)&h;
}
__device__ __forceinline__ void split_hi_lo(float a, u16& hi, u16& lo) {
    __hip_bfloat16 h = __float2bfloat16(a);
    float hf = __bfloat162float(h);
    __hip_bfloat16 l = __float2bfloat16(a - hf);
    hi = *(u16*)&h; lo = *(u16*)&l;
}
// acc.{x,y} += unpacked bf16 pair (packed f32 add: 1 VALU inst, same add order)
__device__ __forceinline__ void pk_acc(f32x2& acc, u32 v) {
    f32x2 val;
    val.x = __uint_as_float(v << 16);
    val.y = __uint_as_float(v & 0xffff0000u);
    asm("v_pk_add_f32 %0, %0, %1" : "+v"(acc) : "v"(val));
}

// ============================ utilities

__global__ void zero_kernel(int* __restrict__ p, int n) {
    int i = blockIdx.x * blockDim.x + threadIdx.x;
    if (i < n) p[i] = 0;
}

// out-degree histogram: 100k L2-resident counters, low contention
__global__ void degree_src(const int* __restrict__ src, int* __restrict__ cnt, int E) {
    for (int i = blockIdx.x * blockDim.x + threadIdx.x; i < E; i += gridDim.x * blockDim.x)
        atomicAdd(&cnt[src[i]], 1);
}

// ============================ CSR build: dst-only radix partition
// Buckets of 256 nodes: bucket = dst>>8, K = ceil(N/256). NB partition blocks.
// Bucket-major: BH[k*NB + b]  ->  OFS[k*NB] == global start of bucket k.

__global__ __launch_bounds__(256)
void part_hist(const int* __restrict__ dst, int* __restrict__ bh,
               int E, int K, int NB) {
    const int b = blockIdx.x;
    extern __shared__ int lh[];                 // K ints
    for (int i = threadIdx.x; i < K; i += 256) lh[i] = 0;
    __syncthreads();
    const int lo = (int)((long long)E * b / NB);
    const int hi = (int)((long long)E * (b + 1) / NB);
    for (int i = lo + threadIdx.x; i < hi; i += 256)
        atomicAdd(&lh[__builtin_nontemporal_load(&dst[i]) >> 8], 1);
    __syncthreads();
    for (int k = threadIdx.x; k < K; k += 256)
        bh[k * NB + b] = lh[k];
}

__global__ __launch_bounds__(256)
void part_scatter(const int* __restrict__ src, const int* __restrict__ dst,
                  const int* __restrict__ ofs, u32* __restrict__ pairs,
                  int E, int K, int NB) {
    const int b = blockIdx.x;
    extern __shared__ int lcur[];               // K ints
    for (int k = threadIdx.x; k < K; k += 256) lcur[k] = ofs[k * NB + b];
    __syncthreads();
    const int lo = (int)((long long)E * b / NB);
    const int hi = (int)((long long)E * (b + 1) / NB);
    for (int i = lo + threadIdx.x; i < hi; i += 256) {
        int d = __builtin_nontemporal_load(&dst[i]);
        int s = __builtin_nontemporal_load(&src[i]);
        int p = atomicAdd(&lcur[d >> 8], 1);
        pairs[p] = ((u32)s << 8) | (u32)(d & 255);
    }
}

// fused per-bucket: histogram -> in-block prefix (padded to x4) ->
// row_start/row_end/iso/isi -> cursor fill -> pad with index N.
// Bucket k's csr region base = OFS[k*NB] + k*768 (768 = max pad per bucket).
__global__ __launch_bounds__(256)
void bucket_count_fill(const u32* __restrict__ pairs, const int* __restrict__ OFS,
                       const int* __restrict__ cnt_out,
                       int* __restrict__ csr, int* __restrict__ row_start,
                       int* __restrict__ row_end, float* __restrict__ iso,
                       float* __restrict__ isi, int N, int NB, int K, int E) {
    const int k = blockIdx.x, t = threadIdx.x;
    __shared__ int lc[256];
    __shared__ int lpre[256];
    lc[t] = 0;
    __syncthreads();
    const int s0 = OFS[k * NB];
    const int s1 = (k == K - 1) ? E : OFS[(k + 1) * NB];
    for (int i = s0 + t; i < s1; i += 256)
        atomicAdd(&lc[pairs[i] & 255], 1);
    __syncthreads();
    const int c  = lc[t];
    const int cp = (c + 3) & ~3;
    lpre[t] = cp;
    __syncthreads();
    for (int off = 1; off < 256; off <<= 1) {
        int v = (t >= off) ? lpre[t - off] : 0;
        __syncthreads();
        lpre[t] += v;
        __syncthreads();
    }
    const int start = s0 + k * 768 + lpre[t] - cp;
    const int myend = start + cp;
    const int node = k * 256 + t;
    if (node < N) {
        row_start[node] = start;
        row_end[node]   = myend;
        int di = c < 1 ? 1 : c;
        int co = cnt_out[node];
        int dd = co < 1 ? 1 : co;
        isi[node] = rsqrtf((float)di);
        iso[node] = rsqrtf((float)dd);
    }
    __syncthreads();
    lc[t] = start;                  // reuse as cursor
    __syncthreads();
    for (int i = s0 + t; i < s1; i += 256) {    // pairs now L2-hot
        u32 pr = pairs[i];
        int p = atomicAdd(&lc[pr & 255], 1);
        csr[p] = (int)(pr >> 8);
    }
    __syncthreads();
    if (node < N) {
        for (int q = lc[t]; q < myend; ++q) csr[q] = N;   // <=3 pads
    }
}

// ============================ edge-histogram scan (M = K*NB elements)

__global__ __launch_bounds__(256)
void scan_pass1(const int* __restrict__ in, int* __restrict__ blocksum, int M) {
    const int b = blockIdx.x, t = threadIdx.x;
    const int base = b * 1024 + t * 4;
    int s = 0;
#pragma unroll
    for (int j = 0; j < 4; ++j) {
        int idx = base + j;
        if (idx < M) s += in[idx];
    }
#pragma unroll
    for (int off = 32; off >= 1; off >>= 1) s += __shfl_xor(s, off);
    __shared__ int wsum[4];
    if ((t & 63) == 0) wsum[t >> 6] = s;
    __syncthreads();
    if (t == 0) blocksum[b] = wsum[0] + wsum[1] + wsum[2] + wsum[3];
}

__global__ __launch_bounds__(1024)
void scan_g2(int* __restrict__ a, int nb) {
    __shared__ int s[1024];
    const int t = threadIdx.x;
    int v = (t < nb) ? a[t] : 0;
    s[t] = v;
    __syncthreads();
    for (int off = 1; off < 1024; off <<= 1) {
        int x = (t >= off) ? s[t - off] : 0;
        __syncthreads();
        s[t] += x;
        __syncthreads();
    }
    if (t < nb) a[t] = s[t] - v;    // exclusive
}

__global__ __launch_bounds__(256)
void scan_g3(const int* __restrict__ in, const int* __restrict__ blockoff,
             int* __restrict__ out, int M) {
    __shared__ int ssum[256];
    const int b = blockIdx.x, t = threadIdx.x;
    const int base = b * 1024 + t * 4;
    int c[4];
#pragma unroll
    for (int j = 0; j < 4; ++j) {
        int idx = base + j;
        c[j] = (idx < M) ? in[idx] : 0;
    }
    const int tot = c[0] + c[1] + c[2] + c[3];
    ssum[t] = tot;
    __syncthreads();
    for (int off = 1; off < 256; off <<= 1) {
        int v = (t >= off) ? ssum[t - off] : 0;
        __syncthreads();
        ssum[t] += v;
        __syncthreads();
    }
    int run = blockoff[b] + ssum[t] - tot;
#pragma unroll
    for (int j = 0; j < 4; ++j) {
        int idx = base + j;
        if (idx < M) { out[idx] = run; run += c[j]; }
    }
}

// ============================ weight prep: Wt[c][k] = bf16(W[k][c])

__global__ __launch_bounds__(128)
void wt_prep_all(const float* __restrict__ W1, const float* __restrict__ W2,
                 const float* __restrict__ W3, u16* __restrict__ Wt1,
                 u16* __restrict__ Wt2, u16* __restrict__ Wt3) {
    const int b = blockIdx.x, k = threadIdx.x;
    if (b < 128)       Wt1[b * 128 + k] = bf16_bits(W1[k * 128 + b]);
    else if (b < 256)  { int c = b - 128; Wt2[c * 128 + k] = bf16_bits(W2[k * 128 + c]); }
    else               { int c = b - 256; Wt3[c * 128 + k] = bf16_bits(W3[k * 64 + c]); }
}

// ============================ MFMA phases
// A: 64 rows x 128 bf16 in LDS, row stride 136. Wt: [C][128] bf16.
// Layout (HW-verified rounds 6-13): A row=lane&15, k=(lane>>4)*8+j;
// B col=lane&15; D col=lane&15, row=(lane>>4)*4+reg.

// two-plane (hi+lo) version — layer 1 only (raw f32 features)
template <int C>
__device__ __forceinline__
void mfma_store2(const u16* sAh, const u16* sAl, const u16* __restrict__ Wt,
                 u16* __restrict__ H, int row0, int N, int t) {
    constexpr int NT = C / 16;
    const int wid = t >> 6, lane = t & 63;
    const int r0 = wid * 16;
    const int arow = r0 + (lane & 15);
    const int kb = (lane >> 4) * 8;

    f32x4 acc[NT];
#pragma unroll
    for (int i = 0; i < NT; ++i) acc[i] = (f32x4){0.f, 0.f, 0.f, 0.f};

    const u16* wbase = Wt + (size_t)(lane & 15) * 128 + kb;

#pragma unroll
    for (int kk = 0; kk < 4; ++kk) {
        short8 ah = *(const short8*)(&sAh[arow * 136 + kk * 32 + kb]);
        short8 al = *(const short8*)(&sAl[arow * 136 + kk * 32 + kb]);
#pragma unroll
        for (int ct = 0; ct < NT; ++ct) {
            short8 bf = *(const short8*)(wbase + ct * 16 * 128 + kk * 32);
            acc[ct] = __builtin_amdgcn_mfma_f32_16x16x32_bf16(ah, bf, acc[ct], 0, 0, 0);
            acc[ct] = __builtin_amdgcn_mfma_f32_16x16x32_bf16(al, bf, acc[ct], 0, 0, 0);
        }
    }

    const int rbase = row0 + r0 + (lane >> 4) * 4;
#pragma unroll
    for (int ct = 0; ct < NT; ++ct) {
        int gcol = ct * 16 + (lane & 15);
#pragma unroll
        for (int r = 0; r < 4; ++r) {
            int grow = rbase + r;
            if (grow < N) H[(size_t)grow * C + gcol] = bf16_bits(acc[ct][r]);
        }
    }
}

// single-plane version — layers 2-3 (activations already bf16-filtered)
template <int C>
__device__ __forceinline__
void mfma_store1(const u16* sA, const u16* __restrict__ Wt,
                 u16* __restrict__ H, int row0, int N, int t) {
    constexpr int NT = C / 16;
    const int wid = t >> 6, lane = t & 63;
    const int r0 = wid * 16;
    const int arow = r0 + (lane & 15);
    const int kb = (lane >> 4) * 8;

    f32x4 acc[NT];
#pragma unroll
    for (int i = 0; i < NT; ++i) acc[i] = (f32x4){0.f, 0.f, 0.f, 0.f};

    const u16* wbase = Wt + (size_t)(lane & 15) * 128 + kb;

#pragma unroll
    for (int kk = 0; kk < 4; ++kk) {
        short8 a = *(const short8*)(&sA[arow * 136 + kk * 32 + kb]);
#pragma unroll
        for (int ct = 0; ct < NT; ++ct) {
            short8 bf = *(const short8*)(wbase + ct * 16 * 128 + kk * 32);
            acc[ct] = __builtin_amdgcn_mfma_f32_16x16x32_bf16(a, bf, acc[ct], 0, 0, 0);
        }
    }

    const int rbase = row0 + r0 + (lane >> 4) * 4;
#pragma unroll
    for (int ct = 0; ct < NT; ++ct) {
        int gcol = ct * 16 + (lane & 15);
#pragma unroll
        for (int r = 0; r < 4; ++r) {
            int grow = rbase + r;
            if (grow < N) H[(size_t)grow * C + gcol] = bf16_bits(acc[ct][r]);
        }
    }
}

// ============================ fused layer-1 GEMM (absorbs x_prep, hi/lo planes)

__global__ __launch_bounds__(256)
void gemm1_fused(const float* __restrict__ X, const float* __restrict__ iso,
                 const u16* __restrict__ Wt, u16* __restrict__ H, int N) {
    __shared__ u16 sAh[64 * 136];
    __shared__ u16 sAl[64 * 136];
    const int t = threadIdx.x;
    const int row0 = blockIdx.x * 64;

    if (blockIdx.x == 0 && t < 64) ((u32*)H)[(size_t)N * 64 + t] = 0;   // zero pad row

    for (int i = t; i < 2048; i += 256) {       // 64 rows x 32 float4-chunks
        int r = i >> 5, kv = (i & 31) << 2;
        int gr = row0 + r;
        if (gr >= N) gr = N - 1;
        float s = iso[gr];
        float4 x = *(const float4*)(X + (size_t)gr * 128 + kv);
        u16 h0, l0, h1, l1, h2, l2, h3, l3;
        split_hi_lo(x.x * s, h0, l0);
        split_hi_lo(x.y * s, h1, l1);
        split_hi_lo(x.z * s, h2, l2);
        split_hi_lo(x.w * s, h3, l3);
        uint2 hp = make_uint2((u32)h0 | ((u32)h1 << 16), (u32)h2 | ((u32)h3 << 16));
        uint2 lp = make_uint2((u32)l0 | ((u32)l1 << 16), (u32)l2 | ((u32)l3 << 16));
        *(uint2*)(&sAh[r * 136 + kv]) = hp;
        *(uint2*)(&sAl[r * 136 + kv]) = lp;
    }
    __syncthreads();
    mfma_store2<128>(sAh, sAl, Wt, H, row0, N, t);
}

// ============================ layers 2-3 GEMM: single bf16 plane from global

template <int C>
__global__ __launch_bounds__(256)
void gemm_mfma(const u16* __restrict__ A,
               const u16* __restrict__ Wt, u16* __restrict__ H, int N) {
    __shared__ u16 sA[64 * 136];
    const int t = threadIdx.x;
    const int row0 = blockIdx.x * 64;

    if (blockIdx.x == 0 && t < C / 2) ((u32*)H)[(size_t)N * (C / 2) + t] = 0;  // zero pad row

    for (int c = t; c < 1024; c += 256) {       // 64 rows x 16 uint4-chunks
        int r = c >> 4, kc = c & 15;
        int gr = row0 + r;
        if (gr >= N) gr = N - 1;
        *(uint4*)(&sA[r * 136 + kc * 8]) = *(const uint4*)(A + (size_t)gr * 128 + kc * 8);
    }
    __syncthreads();
    mfma_store1<C>(sA, Wt, H, row0, N, t);
}

// ============================ wide gather: 4 rows (edges) per dwordx4 load
// lane l reads bytes (l&15)*16 of row csr[e + 4g + (l>>4)]; acc = 8 cols/lane.
// CSR rows are padded to multiples of 4 with index N (zero row).

__device__ __forceinline__
void gather128w(const u16* __restrict__ Hin, const int* __restrict__ csr,
                int rs, int re, int lane, f32x2* acc) {
    const int sub = lane >> 4;
    const int cb  = (lane & 15) * 8;            // u16 offset within row
    int e = rs;
    while (e < re) {
        int nloc = re - e;
        if (nloc > 64) nloc = 64;               // nloc is a multiple of 4
        int idx = (lane < nloc) ? __builtin_nontemporal_load(&csr[e + lane]) : 0;
        int j = 0;
        for (; j + 16 <= nloc; j += 16) {
            int r0 = __shfl(idx, j + sub);
            int r1 = __shfl(idx, j + 4 + sub);
            int r2 = __shfl(idx, j + 8 + sub);
            int r3 = __shfl(idx, j + 12 + sub);
            uint4 v0 = *(const uint4*)(Hin + (size_t)r0 * 128 + cb);
            uint4 v1 = *(const uint4*)(Hin + (size_t)r1 * 128 + cb);
            uint4 v2 = *(const uint4*)(Hin + (size_t)r2 * 128 + cb);
            uint4 v3 = *(const uint4*)(Hin + (size_t)r3 * 128 + cb);
            pk_acc(acc[0], v0.x); pk_acc(acc[1], v0.y); pk_acc(acc[2], v0.z); pk_acc(acc[3], v0.w);
            pk_acc(acc[0], v1.x); pk_acc(acc[1], v1.y); pk_acc(acc[2], v1.z); pk_acc(acc[3], v1.w);
            pk_acc(acc[0], v2.x); pk_acc(acc[1], v2.y); pk_acc(acc[2], v2.z); pk_acc(acc[3], v2.w);
            pk_acc(acc[0], v3.x); pk_acc(acc[1], v3.y); pk_acc(acc[2], v3.z); pk_acc(acc[3], v3.w);
        }
        for (; j < nloc; j += 4) {
            int r0 = __shfl(idx, j + sub);
            uint4 v0 = *(const uint4*)(Hin + (size_t)r0 * 128 + cb);
            pk_acc(acc[0], v0.x); pk_acc(acc[1], v0.y); pk_acc(acc[2], v0.z); pk_acc(acc[3], v0.w);
        }
        e += nloc;
    }
}

// ============================ aggregation layers 1-2 (one wave per node)
// out = relu(agg*isi + b) * iso  ->  single bf16 plane

__global__ __launch_bounds__(256)
void agg_relu(const u16* __restrict__ H, const int* __restrict__ row_start,
              const int* __restrict__ row_end,
              const int* __restrict__ csr_src, const float* __restrict__ isi,
              const float* __restrict__ iso, const float* __restrict__ bias,
              u16* __restrict__ A, int N) {
    const int wid  = (int)((blockIdx.x * (size_t)blockDim.x + threadIdx.x) >> 6);
    const int lane = threadIdx.x & 63;
    if (wid >= N) return;
    const int rs = row_start[wid];
    const int re = row_end[wid];

    f32x2 acc[4];
#pragma unroll
    for (int i = 0; i < 4; ++i) { acc[i].x = 0.f; acc[i].y = 0.f; }
    gather128w(H, csr_src, rs, re, lane, acc);

    // reduce over the 4 edge-subsets (lanes differing in bits 4,5)
#pragma unroll
    for (int i = 0; i < 4; ++i) {
        acc[i].x += __shfl_xor(acc[i].x, 16); acc[i].y += __shfl_xor(acc[i].y, 16);
        acc[i].x += __shfl_xor(acc[i].x, 32); acc[i].y += __shfl_xor(acc[i].y, 32);
    }

    if (lane < 16) {
        const float sc = isi[wid], so = iso[wid];
        float4 ba = *(const float4*)(bias + lane * 8);
        float4 bb = *(const float4*)(bias + lane * 8 + 4);
        float o[8];
        o[0] = acc[0].x * sc + ba.x; o[1] = acc[0].y * sc + ba.y;
        o[2] = acc[1].x * sc + ba.z; o[3] = acc[1].y * sc + ba.w;
        o[4] = acc[2].x * sc + bb.x; o[5] = acc[2].y * sc + bb.y;
        o[6] = acc[3].x * sc + bb.z; o[7] = acc[3].y * sc + bb.w;
        u32 hp[4];
#pragma unroll
        for (int i = 0; i < 4; ++i) {
            u16 h0 = bf16_bits(fmaxf(o[2 * i], 0.f) * so);
            u16 h1 = bf16_bits(fmaxf(o[2 * i + 1], 0.f) * so);
            hp[i] = (u32)h0 | ((u32)h1 << 16);
        }
        *(uint4*)(A + (size_t)wid * 128 + lane * 8) = *(uint4*)hp;
    }
}

// ============================ final aggregation: 64-col gather + log_softmax
// 4 rows (128 B each) per dwordx2 wave-load: lane covers cols (lane&15)*4..+3.

__global__ __launch_bounds__(256)
void agg_final(const u16* __restrict__ H, const int* __restrict__ row_start,
               const int* __restrict__ row_end,
               const int* __restrict__ csr_src, const float* __restrict__ isi,
               const float* __restrict__ bias, float* __restrict__ Out, int N) {
    const int wid  = (int)((blockIdx.x * (size_t)blockDim.x + threadIdx.x) >> 6);
    const int lane = threadIdx.x & 63;
    if (wid >= N) return;
    const int rs = row_start[wid];
    const int re = row_end[wid];
    const int sub = lane >> 4;
    const int cb  = (lane & 15) * 4;            // u16 offset within 64-col row

    f32x2 a0, a1;
    a0.x = a0.y = a1.x = a1.y = 0.f;
    int e = rs;
    while (e < re) {
        int nloc = re - e;
        if (nloc > 64) nloc = 64;
        int idx = (lane < nloc) ? __builtin_nontemporal_load(&csr_src[e + lane]) : 0;
        int j = 0;
        for (; j + 16 <= nloc; j += 16) {
            int r0 = __shfl(idx, j + sub);
            int r1 = __shfl(idx, j + 4 + sub);
            int r2 = __shfl(idx, j + 8 + sub);
            int r3 = __shfl(idx, j + 12 + sub);
            uint2 v0 = *(const uint2*)(H + (size_t)r0 * 64 + cb);
            uint2 v1 = *(const uint2*)(H + (size_t)r1 * 64 + cb);
            uint2 v2 = *(const uint2*)(H + (size_t)r2 * 64 + cb);
            uint2 v3 = *(const uint2*)(H + (size_t)r3 * 64 + cb);
            pk_acc(a0, v0.x); pk_acc(a1, v0.y);
            pk_acc(a0, v1.x); pk_acc(a1, v1.y);
            pk_acc(a0, v2.x); pk_acc(a1, v2.y);
            pk_acc(a0, v3.x); pk_acc(a1, v3.y);
        }
        for (; j < nloc; j += 4) {
            int r0 = __shfl(idx, j + sub);
            uint2 v0 = *(const uint2*)(H + (size_t)r0 * 64 + cb);
            pk_acc(a0, v0.x); pk_acc(a1, v0.y);
        }
        e += nloc;
    }

    // reduce over 4 edge-subsets
    a0.x += __shfl_xor(a0.x, 16); a0.y += __shfl_xor(a0.y, 16);
    a0.x += __shfl_xor(a0.x, 32); a0.y += __shfl_xor(a0.y, 32);
    a1.x += __shfl_xor(a1.x, 16); a1.y += __shfl_xor(a1.y, 16);
    a1.x += __shfl_xor(a1.x, 32); a1.y += __shfl_xor(a1.y, 32);

    // lanes 0-15 hold cols lane*4..+3; softmax across the 16-lane group
    const float sc = isi[wid];
    float4 b4 = *(const float4*)(bias + (lane & 15) * 4);
    float v0 = a0.x * sc + b4.x;
    float v1 = a0.y * sc + b4.y;
    float v2 = a1.x * sc + b4.z;
    float v3 = a1.y * sc + b4.w;
    float m = fmaxf(fmaxf(v0, v1), fmaxf(v2, v3));
#pragma unroll
    for (int off = 8; off >= 1; off >>= 1) m = fmaxf(m, __shfl_xor(m, off));
    float ss = expf(v0 - m) + expf(v1 - m) + expf(v2 - m) + expf(v3 - m);
#pragma unroll
    for (int off = 8; off >= 1; off >>= 1) ss += __shfl_xor(ss, off);
    float lg = m + logf(ss);
    if (lane < 16) {
        float4 o = make_float4(v0 - lg, v1 - lg, v2 - lg, v3 - lg);
        *(float4*)(Out + (size_t)wid * 64 + lane * 4) = o;
    }
}

// ============================ launch

extern "C" void kernel_launch(void* const* d_in, const int* in_sizes, int n_in,
                              void* d_out, int out_size, void* d_ws, size_t ws_size,
                              hipStream_t stream) {
    const float* features = (const float*)d_in[0];
    const int*   src      = (const int*)d_in[1];
    const int*   dst      = (const int*)d_in[2];
    const float* W1       = (const float*)d_in[3];
    const float* b1       = (const float*)d_in[4];
    const float* W2       = (const float*)d_in[5];
    const float* b2       = (const float*)d_in[6];
    const float* W3       = (const float*)d_in[7];
    const float* b3       = (const float*)d_in[8];
    float*       out      = (float*)d_out;

    const int N  = in_sizes[0] / IN_C;   // 100000
    const int E  = in_sizes[1];          // 1600000
    const int K  = (N + 255) >> 8;       // 391 buckets of 256 nodes
    const int NB = 256;                  // partition blocks
    const int M  = K * NB;               // dst histogram size (~100k)
    const int nbe = (M + 1023) / 1024;

    char* ws = (char*)d_ws;
    const size_t SLOT = 400128;          // >= (N+1)*4, 128B-aligned
    int*   cnt_out   = (int*)(ws + 0 * SLOT);
    int*   row_end   = (int*)(ws + 1 * SLOT);
    int*   row_start = (int*)(ws + 2 * SLOT);
    float* iso       = (float*)(ws + 3 * SLOT);
    float* isi       = (float*)(ws + 4 * SLOT);
    int*   eblocksum = (int*)(ws + 5 * SLOT);            // <=1024 ints
    int*   csr       = (int*)(ws + 6 * SLOT);            // E + K*768 ints (7.6MB, slot 8MB)
    char*  p         = ws + 6 * SLOT + 8000000;
    int*   BH        = (int*)p;                          // M ints (400KB)
    int*   OFS       = (int*)(p + 500000);               // M ints (400KB)
    u32*   pairs     = (u32*)(p + 1000000);              // E u32 (6.4MB)
    u16*   Hb        = (u16*)(p + 7400000);              // (N+1)*128 bf16 (25.6MB+)
    u16*   Ab        = (u16*)(p + 33100000);             // N*128 bf16 (25.6MB)
    u16*   Wt1       = (u16*)(p + 58700000);             // 128*128 bf16
    u16*   Wt2       = Wt1 + 128 * 128;
    u16*   Wt3       = Wt2 + 128 * 128;                  // 64*128 bf16

    const size_t ldsK = (size_t)K * sizeof(int);

    // ---- CSR build: dst-only radix partition + fused per-bucket fill ----
    zero_kernel<<<(N + 255) / 256, 256, 0, stream>>>(cnt_out, N);
    degree_src<<<1024, 256, 0, stream>>>(src, cnt_out, E);
    part_hist<<<NB, 256, ldsK, stream>>>(dst, BH, E, K, NB);
    scan_pass1<<<nbe, 256, 0, stream>>>(BH, eblocksum, M);
    scan_g2<<<1, 1024, 0, stream>>>(eblocksum, nbe);
    scan_g3<<<nbe, 256, 0, stream>>>(BH, eblocksum, OFS, M);
    part_scatter<<<NB, 256, ldsK, stream>>>(src, dst, OFS, pairs, E, K, NB);
    bucket_count_fill<<<K, 256, 0, stream>>>(pairs, OFS, cnt_out, csr, row_start,
                                             row_end, iso, isi, N, NB, K, E);

    // ---- weights ----
    wt_prep_all<<<320, 128, 0, stream>>>(W1, W2, W3, Wt1, Wt2, Wt3);

    // ---- 3-layer GCN ----
    const int gblocks = (N + 63) / 64;
    const int ablocks = (int)(((size_t)N * 64 + 255) / 256);

    gemm1_fused<<<gblocks, 256, 0, stream>>>(features, iso, Wt1, Hb, N);
    agg_relu<<<ablocks, 256, 0, stream>>>(Hb, row_start, row_end, csr, isi, iso, b1, Ab, N);
    gemm_mfma<128><<<gblocks, 256, 0, stream>>>(Ab, Wt2, Hb, N);
    agg_relu<<<ablocks, 256, 0, stream>>>(Hb, row_start, row_end, csr, isi, iso, b2, Ab, N);
    gemm_mfma<64><<<gblocks, 256, 0, stream>>>(Ab, Wt3, Hb, N);
    agg_final<<<ablocks, 256, 0, stream>>>(Hb, row_start, row_end, csr, isi, b3, out, N);
}

// Round 15
// 391.198 us; speedup vs baseline: 1.1100x; 1.1100x over previous
//
#include <hip/hip_runtime.h>
#include <hip/hip_bf16.h>

#define IN_C 128
#define HID_C 128
#define OUT_C 64

typedef unsigned short u16;
typedef unsigned int   u32;
typedef __attribute__((ext_vector_type(8))) short short8;
typedef __attribute__((ext_vector_type(4))) float f32x4;
typedef __attribute__((ext_vector_type(2))) float f32x2;

__device__ __forceinline__ u16 bf16_bits(float x) {
    __hip_bfloat16 h = __float2bfloat16(x);   // RNE
    return *(u16*)&h;
}
__device__ __forceinline__ void split_hi_lo(float a, u16& hi, u16& lo) {
    __hip_bfloat16 h = __float2bfloat16(a);
    float hf = __bfloat162float(h);
    __hip_bfloat16 l = __float2bfloat16(a - hf);
    hi = *(u16*)&h; lo = *(u16*)&l;
}
// acc.{x,y} += unpacked bf16 pair (packed f32 add: 1 VALU inst, same add order)
__device__ __forceinline__ void pk_acc(f32x2& acc, u32 v) {
    f32x2 val;
    val.x = __uint_as_float(v << 16);
    val.y = __uint_as_float(v & 0xffff0000u);
    asm("v_pk_add_f32 %0, %0, %1" : "+v"(acc) : "v"(val));
}

// ============================ utilities

__global__ void zero_kernel(int* __restrict__ p, int n) {
    int i = blockIdx.x * blockDim.x + threadIdx.x;
    if (i < n) p[i] = 0;
}

// out-degree histogram: 100k L2-resident counters, low contention
__global__ void degree_src(const int* __restrict__ src, int* __restrict__ cnt, int E) {
    for (int i = blockIdx.x * blockDim.x + threadIdx.x; i < E; i += gridDim.x * blockDim.x)
        atomicAdd(&cnt[src[i]], 1);
}

// ============================ CSR build: dst-only radix partition
// Buckets of 256 nodes: bucket = dst>>8, K = ceil(N/256). NB partition blocks.
// Bucket-major: BH[k*NB + b]  ->  OFS[k*NB] == global start of bucket k.

__global__ __launch_bounds__(256)
void part_hist(const int* __restrict__ dst, int* __restrict__ bh,
               int E, int K, int NB) {
    const int b = blockIdx.x;
    extern __shared__ int lh[];                 // K ints
    for (int i = threadIdx.x; i < K; i += 256) lh[i] = 0;
    __syncthreads();
    const int lo = (int)((long long)E * b / NB);
    const int hi = (int)((long long)E * (b + 1) / NB);
    for (int i = lo + threadIdx.x; i < hi; i += 256)
        atomicAdd(&lh[__builtin_nontemporal_load(&dst[i]) >> 8], 1);
    __syncthreads();
    for (int k = threadIdx.x; k < K; k += 256)
        bh[k * NB + b] = lh[k];
}

__global__ __launch_bounds__(256)
void part_scatter(const int* __restrict__ src, const int* __restrict__ dst,
                  const int* __restrict__ ofs, u32* __restrict__ pairs,
                  int E, int K, int NB) {
    const int b = blockIdx.x;
    extern __shared__ int lcur[];               // K ints
    for (int k = threadIdx.x; k < K; k += 256) lcur[k] = ofs[k * NB + b];
    __syncthreads();
    const int lo = (int)((long long)E * b / NB);
    const int hi = (int)((long long)E * (b + 1) / NB);
    for (int i = lo + threadIdx.x; i < hi; i += 256) {
        int d = __builtin_nontemporal_load(&dst[i]);
        int s = __builtin_nontemporal_load(&src[i]);
        int p = atomicAdd(&lcur[d >> 8], 1);
        pairs[p] = ((u32)s << 8) | (u32)(d & 255);
    }
}

// fused per-bucket: histogram -> in-block prefix (padded to x4) ->
// row_start/row_end/iso/isi -> cursor fill -> pad with index N.
// Bucket k's csr region base = OFS[k*NB] + k*768 (768 = max pad per bucket).
__global__ __launch_bounds__(256)
void bucket_count_fill(const u32* __restrict__ pairs, const int* __restrict__ OFS,
                       const int* __restrict__ cnt_out,
                       int* __restrict__ csr, int* __restrict__ row_start,
                       int* __restrict__ row_end, float* __restrict__ iso,
                       float* __restrict__ isi, int N, int NB, int K, int E) {
    const int k = blockIdx.x, t = threadIdx.x;
    __shared__ int lc[256];
    __shared__ int lpre[256];
    lc[t] = 0;
    __syncthreads();
    const int s0 = OFS[k * NB];
    const int s1 = (k == K - 1) ? E : OFS[(k + 1) * NB];
    for (int i = s0 + t; i < s1; i += 256)
        atomicAdd(&lc[pairs[i] & 255], 1);
    __syncthreads();
    const int c  = lc[t];
    const int cp = (c + 3) & ~3;
    lpre[t] = cp;
    __syncthreads();
    for (int off = 1; off < 256; off <<= 1) {
        int v = (t >= off) ? lpre[t - off] : 0;
        __syncthreads();
        lpre[t] += v;
        __syncthreads();
    }
    const int start = s0 + k * 768 + lpre[t] - cp;
    const int myend = start + cp;
    const int node = k * 256 + t;
    if (node < N) {
        row_start[node] = start;
        row_end[node]   = myend;
        int di = c < 1 ? 1 : c;
        int co = cnt_out[node];
        int dd = co < 1 ? 1 : co;
        isi[node] = rsqrtf((float)di);
        iso[node] = rsqrtf((float)dd);
    }
    __syncthreads();
    lc[t] = start;                  // reuse as cursor
    __syncthreads();
    for (int i = s0 + t; i < s1; i += 256) {    // pairs now L2-hot
        u32 pr = pairs[i];
        int p = atomicAdd(&lc[pr & 255], 1);
        csr[p] = (int)(pr >> 8);
    }
    __syncthreads();
    if (node < N) {
        for (int q = lc[t]; q < myend; ++q) csr[q] = N;   // <=3 pads
    }
}

// ============================ edge-histogram scan (M = K*NB elements)

__global__ __launch_bounds__(256)
void scan_pass1(const int* __restrict__ in, int* __restrict__ blocksum, int M) {
    const int b = blockIdx.x, t = threadIdx.x;
    const int base = b * 1024 + t * 4;
    int s = 0;
#pragma unroll
    for (int j = 0; j < 4; ++j) {
        int idx = base + j;
        if (idx < M) s += in[idx];
    }
#pragma unroll
    for (int off = 32; off >= 1; off >>= 1) s += __shfl_xor(s, off);
    __shared__ int wsum[4];
    if ((t & 63) == 0) wsum[t >> 6] = s;
    __syncthreads();
    if (t == 0) blocksum[b] = wsum[0] + wsum[1] + wsum[2] + wsum[3];
}

__global__ __launch_bounds__(1024)
void scan_g2(int* __restrict__ a, int nb) {
    __shared__ int s[1024];
    const int t = threadIdx.x;
    int v = (t < nb) ? a[t] : 0;
    s[t] = v;
    __syncthreads();
    for (int off = 1; off < 1024; off <<= 1) {
        int x = (t >= off) ? s[t - off] : 0;
        __syncthreads();
        s[t] += x;
        __syncthreads();
    }
    if (t < nb) a[t] = s[t] - v;    // exclusive
}

__global__ __launch_bounds__(256)
void scan_g3(const int* __restrict__ in, const int* __restrict__ blockoff,
             int* __restrict__ out, int M) {
    __shared__ int ssum[256];
    const int b = blockIdx.x, t = threadIdx.x;
    const int base = b * 1024 + t * 4;
    int c[4];
#pragma unroll
    for (int j = 0; j < 4; ++j) {
        int idx = base + j;
        c[j] = (idx < M) ? in[idx] : 0;
    }
    const int tot = c[0] + c[1] + c[2] + c[3];
    ssum[t] = tot;
    __syncthreads();
    for (int off = 1; off < 256; off <<= 1) {
        int v = (t >= off) ? ssum[t - off] : 0;
        __syncthreads();
        ssum[t] += v;
        __syncthreads();
    }
    int run = blockoff[b] + ssum[t] - tot;
#pragma unroll
    for (int j = 0; j < 4; ++j) {
        int idx = base + j;
        if (idx < M) { out[idx] = run; run += c[j]; }
    }
}

// ============================ weight prep: Wt[c][k] = bf16(W[k][c])

__global__ __launch_bounds__(128)
void wt_prep_all(const float* __restrict__ W1, const float* __restrict__ W2,
                 const float* __restrict__ W3, u16* __restrict__ Wt1,
                 u16* __restrict__ Wt2, u16* __restrict__ Wt3) {
    const int b = blockIdx.x, k = threadIdx.x;
    if (b < 128)       Wt1[b * 128 + k] = bf16_bits(W1[k * 128 + b]);
    else if (b < 256)  { int c = b - 128; Wt2[c * 128 + k] = bf16_bits(W2[k * 128 + c]); }
    else               { int c = b - 256; Wt3[c * 128 + k] = bf16_bits(W3[k * 64 + c]); }
}

// ============================ MFMA phases
// A: 64 rows x 128 bf16 in LDS, row stride 136. Wt: [C][128] bf16.
// Layout (HW-verified rounds 6-13): A row=lane&15, k=(lane>>4)*8+j;
// B col=lane&15; D col=lane&15, row=(lane>>4)*4+reg.

// two-plane (hi+lo) version — layer 1 only (raw f32 features)
template <int C>
__device__ __forceinline__
void mfma_store2(const u16* sAh, const u16* sAl, const u16* __restrict__ Wt,
                 u16* __restrict__ H, int row0, int N, int t) {
    constexpr int NT = C / 16;
    const int wid = t >> 6, lane = t & 63;
    const int r0 = wid * 16;
    const int arow = r0 + (lane & 15);
    const int kb = (lane >> 4) * 8;

    f32x4 acc[NT];
#pragma unroll
    for (int i = 0; i < NT; ++i) acc[i] = (f32x4){0.f, 0.f, 0.f, 0.f};

    const u16* wbase = Wt + (size_t)(lane & 15) * 128 + kb;

#pragma unroll
    for (int kk = 0; kk < 4; ++kk) {
        short8 ah = *(const short8*)(&sAh[arow * 136 + kk * 32 + kb]);
        short8 al = *(const short8*)(&sAl[arow * 136 + kk * 32 + kb]);
#pragma unroll
        for (int ct = 0; ct < NT; ++ct) {
            short8 bf = *(const short8*)(wbase + ct * 16 * 128 + kk * 32);
            acc[ct] = __builtin_amdgcn_mfma_f32_16x16x32_bf16(ah, bf, acc[ct], 0, 0, 0);
            acc[ct] = __builtin_amdgcn_mfma_f32_16x16x32_bf16(al, bf, acc[ct], 0, 0, 0);
        }
    }

    const int rbase = row0 + r0 + (lane >> 4) * 4;
#pragma unroll
    for (int ct = 0; ct < NT; ++ct) {
        int gcol = ct * 16 + (lane & 15);
#pragma unroll
        for (int r = 0; r < 4; ++r) {
            int grow = rbase + r;
            if (grow < N) H[(size_t)grow * C + gcol] = bf16_bits(acc[ct][r]);
        }
    }
}

// single-plane version — layers 2-3 (activations already bf16-filtered)
template <int C>
__device__ __forceinline__
void mfma_store1(const u16* sA, const u16* __restrict__ Wt,
                 u16* __restrict__ H, int row0, int N, int t) {
    constexpr int NT = C / 16;
    const int wid = t >> 6, lane = t & 63;
    const int r0 = wid * 16;
    const int arow = r0 + (lane & 15);
    const int kb = (lane >> 4) * 8;

    f32x4 acc[NT];
#pragma unroll
    for (int i = 0; i < NT; ++i) acc[i] = (f32x4){0.f, 0.f, 0.f, 0.f};

    const u16* wbase = Wt + (size_t)(lane & 15) * 128 + kb;

#pragma unroll
    for (int kk = 0; kk < 4; ++kk) {
        short8 a = *(const short8*)(&sA[arow * 136 + kk * 32 + kb]);
#pragma unroll
        for (int ct = 0; ct < NT; ++ct) {
            short8 bf = *(const short8*)(wbase + ct * 16 * 128 + kk * 32);
            acc[ct] = __builtin_amdgcn_mfma_f32_16x16x32_bf16(a, bf, acc[ct], 0, 0, 0);
        }
    }

    const int rbase = row0 + r0 + (lane >> 4) * 4;
#pragma unroll
    for (int ct = 0; ct < NT; ++ct) {
        int gcol = ct * 16 + (lane & 15);
#pragma unroll
        for (int r = 0; r < 4; ++r) {
            int grow = rbase + r;
            if (grow < N) H[(size_t)grow * C + gcol] = bf16_bits(acc[ct][r]);
        }
    }
}

// ============================ fused layer-1 GEMM (absorbs x_prep, hi/lo planes)

__global__ __launch_bounds__(256)
void gemm1_fused(const float* __restrict__ X, const float* __restrict__ iso,
                 const u16* __restrict__ Wt, u16* __restrict__ H, int N) {
    __shared__ u16 sAh[64 * 136];
    __shared__ u16 sAl[64 * 136];
    const int t = threadIdx.x;
    const int row0 = blockIdx.x * 64;

    if (blockIdx.x == 0 && t < 64) ((u32*)H)[(size_t)N * 64 + t] = 0;   // zero pad row

    for (int i = t; i < 2048; i += 256) {       // 64 rows x 32 float4-chunks
        int r = i >> 5, kv = (i & 31) << 2;
        int gr = row0 + r;
        if (gr >= N) gr = N - 1;
        float s = iso[gr];
        float4 x = *(const float4*)(X + (size_t)gr * 128 + kv);
        u16 h0, l0, h1, l1, h2, l2, h3, l3;
        split_hi_lo(x.x * s, h0, l0);
        split_hi_lo(x.y * s, h1, l1);
        split_hi_lo(x.z * s, h2, l2);
        split_hi_lo(x.w * s, h3, l3);
        uint2 hp = make_uint2((u32)h0 | ((u32)h1 << 16), (u32)h2 | ((u32)h3 << 16));
        uint2 lp = make_uint2((u32)l0 | ((u32)l1 << 16), (u32)l2 | ((u32)l3 << 16));
        *(uint2*)(&sAh[r * 136 + kv]) = hp;
        *(uint2*)(&sAl[r * 136 + kv]) = lp;
    }
    __syncthreads();
    mfma_store2<128>(sAh, sAl, Wt, H, row0, N, t);
}

// ============================ layers 2-3 GEMM: single bf16 plane from global

template <int C>
__global__ __launch_bounds__(256)
void gemm_mfma(const u16* __restrict__ A,
               const u16* __restrict__ Wt, u16* __restrict__ H, int N) {
    __shared__ u16 sA[64 * 136];
    const int t = threadIdx.x;
    const int row0 = blockIdx.x * 64;

    if (blockIdx.x == 0 && t < C / 2) ((u32*)H)[(size_t)N * (C / 2) + t] = 0;  // zero pad row

    for (int c = t; c < 1024; c += 256) {       // 64 rows x 16 uint4-chunks
        int r = c >> 4, kc = c & 15;
        int gr = row0 + r;
        if (gr >= N) gr = N - 1;
        *(uint4*)(&sA[r * 136 + kc * 8]) = *(const uint4*)(A + (size_t)gr * 128 + kc * 8);
    }
    __syncthreads();
    mfma_store1<C>(sA, Wt, H, row0, N, t);
}

// ============================ wide gather: 4 rows (edges) per dwordx4 load
// lane l reads bytes (l&15)*16 of row csr[e + 4g + (l>>4)]; acc = 8 cols/lane.
// CSR rows are padded to multiples of 4 with index N (zero row).

__device__ __forceinline__
void gather128w(const u16* __restrict__ Hin, const int* __restrict__ csr,
                int rs, int re, int lane, f32x2* acc) {
    const int sub = lane >> 4;
    const int cb  = (lane & 15) * 8;            // u16 offset within row
    int e = rs;
    while (e < re) {
        int nloc = re - e;
        if (nloc > 64) nloc = 64;               // nloc is a multiple of 4
        int idx = (lane < nloc) ? __builtin_nontemporal_load(&csr[e + lane]) : 0;
        int j = 0;
        for (; j + 16 <= nloc; j += 16) {
            int r0 = __shfl(idx, j + sub);
            int r1 = __shfl(idx, j + 4 + sub);
            int r2 = __shfl(idx, j + 8 + sub);
            int r3 = __shfl(idx, j + 12 + sub);
            uint4 v0 = *(const uint4*)(Hin + (size_t)r0 * 128 + cb);
            uint4 v1 = *(const uint4*)(Hin + (size_t)r1 * 128 + cb);
            uint4 v2 = *(const uint4*)(Hin + (size_t)r2 * 128 + cb);
            uint4 v3 = *(const uint4*)(Hin + (size_t)r3 * 128 + cb);
            pk_acc(acc[0], v0.x); pk_acc(acc[1], v0.y); pk_acc(acc[2], v0.z); pk_acc(acc[3], v0.w);
            pk_acc(acc[0], v1.x); pk_acc(acc[1], v1.y); pk_acc(acc[2], v1.z); pk_acc(acc[3], v1.w);
            pk_acc(acc[0], v2.x); pk_acc(acc[1], v2.y); pk_acc(acc[2], v2.z); pk_acc(acc[3], v2.w);
            pk_acc(acc[0], v3.x); pk_acc(acc[1], v3.y); pk_acc(acc[2], v3.z); pk_acc(acc[3], v3.w);
        }
        for (; j < nloc; j += 4) {
            int r0 = __shfl(idx, j + sub);
            uint4 v0 = *(const uint4*)(Hin + (size_t)r0 * 128 + cb);
            pk_acc(acc[0], v0.x); pk_acc(acc[1], v0.y); pk_acc(acc[2], v0.z); pk_acc(acc[3], v0.w);
        }
        e += nloc;
    }
}

// ============================ aggregation layers 1-2 (one wave per node)
// out = relu(agg*isi + b) * iso  ->  single bf16 plane

__global__ __launch_bounds__(256)
void agg_relu(const u16* __restrict__ H, const int* __restrict__ row_start,
              const int* __restrict__ row_end,
              const int* __restrict__ csr_src, const float* __restrict__ isi,
              const float* __restrict__ iso, const float* __restrict__ bias,
              u16* __restrict__ A, int N) {
    const int wid  = (int)((blockIdx.x * (size_t)blockDim.x + threadIdx.x) >> 6);
    const int lane = threadIdx.x & 63;
    if (wid >= N) return;
    const int rs = row_start[wid];
    const int re = row_end[wid];

    f32x2 acc[4];
#pragma unroll
    for (int i = 0; i < 4; ++i) { acc[i].x = 0.f; acc[i].y = 0.f; }
    gather128w(H, csr_src, rs, re, lane, acc);

    // reduce over the 4 edge-subsets (lanes differing in bits 4,5)
#pragma unroll
    for (int i = 0; i < 4; ++i) {
        acc[i].x += __shfl_xor(acc[i].x, 16); acc[i].y += __shfl_xor(acc[i].y, 16);
        acc[i].x += __shfl_xor(acc[i].x, 32); acc[i].y += __shfl_xor(acc[i].y, 32);
    }

    if (lane < 16) {
        const float sc = isi[wid], so = iso[wid];
        float4 ba = *(const float4*)(bias + lane * 8);
        float4 bb = *(const float4*)(bias + lane * 8 + 4);
        float o[8];
        o[0] = acc[0].x * sc + ba.x; o[1] = acc[0].y * sc + ba.y;
        o[2] = acc[1].x * sc + ba.z; o[3] = acc[1].y * sc + ba.w;
        o[4] = acc[2].x * sc + bb.x; o[5] = acc[2].y * sc + bb.y;
        o[6] = acc[3].x * sc + bb.z; o[7] = acc[3].y * sc + bb.w;
        u32 hp[4];
#pragma unroll
        for (int i = 0; i < 4; ++i) {
            u16 h0 = bf16_bits(fmaxf(o[2 * i], 0.f) * so);
            u16 h1 = bf16_bits(fmaxf(o[2 * i + 1], 0.f) * so);
            hp[i] = (u32)h0 | ((u32)h1 << 16);
        }
        *(uint4*)(A + (size_t)wid * 128 + lane * 8) = *(uint4*)hp;
    }
}

// ============================ final aggregation: 64-col gather + log_softmax
// 4 rows (128 B each) per dwordx2 wave-load: lane covers cols (lane&15)*4..+3.

__global__ __launch_bounds__(256)
void agg_final(const u16* __restrict__ H, const int* __restrict__ row_start,
               const int* __restrict__ row_end,
               const int* __restrict__ csr_src, const float* __restrict__ isi,
               const float* __restrict__ bias, float* __restrict__ Out, int N) {
    const int wid  = (int)((blockIdx.x * (size_t)blockDim.x + threadIdx.x) >> 6);
    const int lane = threadIdx.x & 63;
    if (wid >= N) return;
    const int rs = row_start[wid];
    const int re = row_end[wid];
    const int sub = lane >> 4;
    const int cb  = (lane & 15) * 4;            // u16 offset within 64-col row

    f32x2 a0, a1;
    a0.x = a0.y = a1.x = a1.y = 0.f;
    int e = rs;
    while (e < re) {
        int nloc = re - e;
        if (nloc > 64) nloc = 64;
        int idx = (lane < nloc) ? __builtin_nontemporal_load(&csr_src[e + lane]) : 0;
        int j = 0;
        for (; j + 16 <= nloc; j += 16) {
            int r0 = __shfl(idx, j + sub);
            int r1 = __shfl(idx, j + 4 + sub);
            int r2 = __shfl(idx, j + 8 + sub);
            int r3 = __shfl(idx, j + 12 + sub);
            uint2 v0 = *(const uint2*)(H + (size_t)r0 * 64 + cb);
            uint2 v1 = *(const uint2*)(H + (size_t)r1 * 64 + cb);
            uint2 v2 = *(const uint2*)(H + (size_t)r2 * 64 + cb);
            uint2 v3 = *(const uint2*)(H + (size_t)r3 * 64 + cb);
            pk_acc(a0, v0.x); pk_acc(a1, v0.y);
            pk_acc(a0, v1.x); pk_acc(a1, v1.y);
            pk_acc(a0, v2.x); pk_acc(a1, v2.y);
            pk_acc(a0, v3.x); pk_acc(a1, v3.y);
        }
        for (; j < nloc; j += 4) {
            int r0 = __shfl(idx, j + sub);
            uint2 v0 = *(const uint2*)(H + (size_t)r0 * 64 + cb);
            pk_acc(a0, v0.x); pk_acc(a1, v0.y);
        }
        e += nloc;
    }

    // reduce over 4 edge-subsets
    a0.x += __shfl_xor(a0.x, 16); a0.y += __shfl_xor(a0.y, 16);
    a0.x += __shfl_xor(a0.x, 32); a0.y += __shfl_xor(a0.y, 32);
    a1.x += __shfl_xor(a1.x, 16); a1.y += __shfl_xor(a1.y, 16);
    a1.x += __shfl_xor(a1.x, 32); a1.y += __shfl_xor(a1.y, 32);

    // lanes 0-15 hold cols lane*4..+3; softmax across the 16-lane group
    const float sc = isi[wid];
    float4 b4 = *(const float4*)(bias + (lane & 15) * 4);
    float v0 = a0.x * sc + b4.x;
    float v1 = a0.y * sc + b4.y;
    float v2 = a1.x * sc + b4.z;
    float v3 = a1.y * sc + b4.w;
    float m = fmaxf(fmaxf(v0, v1), fmaxf(v2, v3));
#pragma unroll
    for (int off = 8; off >= 1; off >>= 1) m = fmaxf(m, __shfl_xor(m, off));
    float ss = expf(v0 - m) + expf(v1 - m) + expf(v2 - m) + expf(v3 - m);
#pragma unroll
    for (int off = 8; off >= 1; off >>= 1) ss += __shfl_xor(ss, off);
    float lg = m + logf(ss);
    if (lane < 16) {
        float4 o = make_float4(v0 - lg, v1 - lg, v2 - lg, v3 - lg);
        *(float4*)(Out + (size_t)wid * 64 + lane * 4) = o;
    }
}

// ============================ launch

extern "C" void kernel_launch(void* const* d_in, const int* in_sizes, int n_in,
                              void* d_out, int out_size, void* d_ws, size_t ws_size,
                              hipStream_t stream) {
    const float* features = (const float*)d_in[0];
    const int*   src      = (const int*)d_in[1];
    const int*   dst      = (const int*)d_in[2];
    const float* W1       = (const float*)d_in[3];
    const float* b1       = (const float*)d_in[4];
    const float* W2       = (const float*)d_in[5];
    const float* b2       = (const float*)d_in[6];
    const float* W3       = (const float*)d_in[7];
    const float* b3       = (const float*)d_in[8];
    float*       out      = (float*)d_out;

    const int N  = in_sizes[0] / IN_C;   // 100000
    const int E  = in_sizes[1];          // 1600000
    const int K  = (N + 255) >> 8;       // 391 buckets of 256 nodes
    const int NB = 256;                  // partition blocks
    const int M  = K * NB;               // dst histogram size (~100k)
    const int nbe = (M + 1023) / 1024;

    char* ws = (char*)d_ws;
    const size_t SLOT = 400128;          // >= (N+1)*4, 256B-aligned (1563*256)
    int*   cnt_out   = (int*)(ws + 0 * SLOT);
    int*   row_end   = (int*)(ws + 1 * SLOT);
    int*   row_start = (int*)(ws + 2 * SLOT);
    float* iso       = (float*)(ws + 3 * SLOT);
    float* isi       = (float*)(ws + 4 * SLOT);
    int*   eblocksum = (int*)(ws + 5 * SLOT);            // <=1024 ints
    int*   csr       = (int*)(ws + 6 * SLOT);            // E + K*768 ints (7.6MB, slot 8MB)
    char*  p         = ws + 6 * SLOT + 8000128;          // 256B-aligned (6*SLOT and 8000128 both x256)
    // All big-buffer offsets below are multiples of 256 B so that Hb/Ab rows
    // (256 B / 128 B) never straddle extra cache lines (R14 lesson: 64B-aligned
    // Hb cost +45% FETCH in the gather).
    int*   BH        = (int*)p;                          // M ints (400KB)
    int*   OFS       = (int*)(p + 500224);               // M ints (400KB)
    u32*   pairs     = (u32*)(p + 1000448);              // E u32 (6.4MB)
    u16*   Hb        = (u16*)(p + 7401472);              // (N+1)*128 bf16 (25.6MB)
    u16*   Ab        = (u16*)(p + 33001728);             // N*128 bf16 (25.6MB)
    u16*   Wt1       = (u16*)(p + 58601728);             // 128*128 bf16
    u16*   Wt2       = Wt1 + 128 * 128;
    u16*   Wt3       = Wt2 + 128 * 128;                  // 64*128 bf16

    const size_t ldsK = (size_t)K * sizeof(int);

    // ---- CSR build: dst-only radix partition + fused per-bucket fill ----
    zero_kernel<<<(N + 255) / 256, 256, 0, stream>>>(cnt_out, N);
    degree_src<<<1024, 256, 0, stream>>>(src, cnt_out, E);
    part_hist<<<NB, 256, ldsK, stream>>>(dst, BH, E, K, NB);
    scan_pass1<<<nbe, 256, 0, stream>>>(BH, eblocksum, M);
    scan_g2<<<1, 1024, 0, stream>>>(eblocksum, nbe);
    scan_g3<<<nbe, 256, 0, stream>>>(BH, eblocksum, OFS, M);
    part_scatter<<<NB, 256, ldsK, stream>>>(src, dst, OFS, pairs, E, K, NB);
    bucket_count_fill<<<K, 256, 0, stream>>>(pairs, OFS, cnt_out, csr, row_start,
                                             row_end, iso, isi, N, NB, K, E);

    // ---- weights ----
    wt_prep_all<<<320, 128, 0, stream>>>(W1, W2, W3, Wt1, Wt2, Wt3);

    // ---- 3-layer GCN ----
    const int gblocks = (N + 63) / 64;
    const int ablocks = (int)(((size_t)N * 64 + 255) / 256);

    gemm1_fused<<<gblocks, 256, 0, stream>>>(features, iso, Wt1, Hb, N);
    agg_relu<<<ablocks, 256, 0, stream>>>(Hb, row_start, row_end, csr, isi, iso, b1, Ab, N);
    gemm_mfma<128><<<gblocks, 256, 0, stream>>>(Ab, Wt2, Hb, N);
    agg_relu<<<ablocks, 256, 0, stream>>>(Hb, row_start, row_end, csr, isi, iso, b2, Ab, N);
    gemm_mfma<64><<<gblocks, 256, 0, stream>>>(Ab, Wt3, Hb, N);
    agg_final<<<ablocks, 256, 0, stream>>>(Hb, row_start, row_end, csr, isi, b3, out, N);
}

// Round 16
// 354.942 us; speedup vs baseline: 1.2233x; 1.1021x over previous
//
#include <hip/hip_runtime.h>
#include <hip/hip_bf16.h>

#define IN_C 128
#define HID_C 128
#define OUT_C 64

typedef unsigned short u16;
typedef unsigned int   u32;
typedef __attribute__((ext_vector_type(8))) short short8;
typedef __attribute__((ext_vector_type(4))) float f32x4;
typedef __attribute__((ext_vector_type(2))) float f32x2;

__device__ __forceinline__ u16 bf16_bits(float x) {
    __hip_bfloat16 h = __float2bfloat16(x);   // RNE
    return *(u16*)&h;
}
__device__ __forceinline__ void split_hi_lo(float a, u16& hi, u16& lo) {
    __hip_bfloat16 h = __float2bfloat16(a);
    float hf = __bfloat162float(h);
    __hip_bfloat16 l = __float2bfloat16(a - hf);
    hi = *(u16*)&h; lo = *(u16*)&l;
}
// acc.{x,y} += unpacked bf16 pair (packed f32 add: 1 VALU inst, same add order)
__device__ __forceinline__ void pk_acc(f32x2& acc, u32 v) {
    f32x2 val;
    val.x = __uint_as_float(v << 16);
    val.y = __uint_as_float(v & 0xffff0000u);
    asm("v_pk_add_f32 %0, %0, %1" : "+v"(acc) : "v"(val));
}

// ============================ CSR build: dual-key contention-free radix partition
// Buckets of 256 nodes: bucket = v>>8, K = ceil(N/256). NB partition blocks.
// Concatenated histogram: dst part [0,K*NB), src part [K*NB, 2K*NB).
// Bucket-major: BH[k*NB + b]  ->  OFS[k*NB] == global start of bucket k.
// (R15 lesson: 1.6M random global atomics for out-degree = 66us; LDS-atomic
//  radix partition of src is ~2x cheaper despite moving more bytes.)

__global__ __launch_bounds__(256)
void part_hist2(const int* __restrict__ src, const int* __restrict__ dst,
                int* __restrict__ bh, int E, int K, int NB) {
    const int b = blockIdx.x;
    extern __shared__ int lh[];                 // 2K ints
    for (int i = threadIdx.x; i < 2 * K; i += 256) lh[i] = 0;
    __syncthreads();
    const int lo = (int)((long long)E * b / NB);
    const int hi = (int)((long long)E * (b + 1) / NB);
    for (int i = lo + threadIdx.x; i < hi; i += 256) {
        int d = __builtin_nontemporal_load(&dst[i]);
        int s = __builtin_nontemporal_load(&src[i]);
        atomicAdd(&lh[d >> 8], 1);
        atomicAdd(&lh[K + (s >> 8)], 1);
    }
    __syncthreads();
    for (int k = threadIdx.x; k < K; k += 256) {
        bh[k * NB + b]       = lh[k];
        bh[(K + k) * NB + b] = lh[K + k];
    }
}

__global__ __launch_bounds__(256)
void part_scatter2(const int* __restrict__ src, const int* __restrict__ dst,
                   const int* __restrict__ ofs, u32* __restrict__ pairs,
                   int E, int K, int NB) {
    const int b = blockIdx.x;
    extern __shared__ int lcur[];               // 2K ints
    for (int k = threadIdx.x; k < 2 * K; k += 256) lcur[k] = ofs[k * NB + b];
    __syncthreads();
    const int lo = (int)((long long)E * b / NB);
    const int hi = (int)((long long)E * (b + 1) / NB);
    for (int i = lo + threadIdx.x; i < hi; i += 256) {
        int d = __builtin_nontemporal_load(&dst[i]);
        int s = __builtin_nontemporal_load(&src[i]);
        int p1 = atomicAdd(&lcur[d >> 8], 1);
        pairs[p1] = ((u32)s << 8) | (u32)(d & 255);
        int p2 = atomicAdd(&lcur[K + (s >> 8)], 1);
        pairs[p2] = (u32)s;                      // src partition starts at E
    }
}

// per-bucket out-degree from src partition -> iso directly (no cnt_out array)
__global__ __launch_bounds__(256)
void bucket_count_src(const u32* __restrict__ pairs, const int* __restrict__ OFS,
                      float* __restrict__ iso, int N, int NB, int K, int E) {
    const int k = blockIdx.x, t = threadIdx.x;
    __shared__ int lc[256];
    lc[t] = 0;
    __syncthreads();
    const int s0 = OFS[(K + k) * NB];
    const int s1 = (k == K - 1) ? 2 * E : OFS[(K + k + 1) * NB];
    for (int i = s0 + t; i < s1; i += 256)
        atomicAdd(&lc[pairs[i] & 255], 1);
    __syncthreads();
    const int node = k * 256 + t;
    if (node < N) {
        int c = lc[t];
        iso[node] = rsqrtf((float)(c < 1 ? 1 : c));
    }
}

// fused per-bucket (dst partition): histogram -> in-block prefix (padded to x4)
// -> row_start/row_end/isi -> cursor fill -> pad with index N.
// Bucket k's csr region base = OFS[k*NB] + k*768 (768 = max pad per bucket).
__global__ __launch_bounds__(256)
void bucket_count_fill(const u32* __restrict__ pairs, const int* __restrict__ OFS,
                       int* __restrict__ csr, int* __restrict__ row_start,
                       int* __restrict__ row_end, float* __restrict__ isi,
                       int N, int NB, int K, int E) {
    const int k = blockIdx.x, t = threadIdx.x;
    __shared__ int lc[256];
    __shared__ int lpre[256];
    lc[t] = 0;
    __syncthreads();
    const int s0 = OFS[k * NB];
    const int s1 = (k == K - 1) ? E : OFS[(k + 1) * NB];
    for (int i = s0 + t; i < s1; i += 256)
        atomicAdd(&lc[pairs[i] & 255], 1);
    __syncthreads();
    const int c  = lc[t];
    const int cp = (c + 3) & ~3;
    lpre[t] = cp;
    __syncthreads();
    for (int off = 1; off < 256; off <<= 1) {
        int v = (t >= off) ? lpre[t - off] : 0;
        __syncthreads();
        lpre[t] += v;
        __syncthreads();
    }
    const int start = s0 + k * 768 + lpre[t] - cp;
    const int myend = start + cp;
    const int node = k * 256 + t;
    if (node < N) {
        row_start[node] = start;
        row_end[node]   = myend;
        isi[node] = rsqrtf((float)(c < 1 ? 1 : c));
    }
    __syncthreads();
    lc[t] = start;                  // reuse as cursor
    __syncthreads();
    for (int i = s0 + t; i < s1; i += 256) {    // pairs now L2-hot
        u32 pr = pairs[i];
        int p = atomicAdd(&lc[pr & 255], 1);
        csr[p] = (int)(pr >> 8);
    }
    __syncthreads();
    if (node < N) {
        for (int q = lc[t]; q < myend; ++q) csr[q] = N;   // <=3 pads
    }
}

// ============================ edge-histogram scan (M = 2K*NB elements)

__global__ __launch_bounds__(256)
void scan_pass1(const int* __restrict__ in, int* __restrict__ blocksum, int M) {
    const int b = blockIdx.x, t = threadIdx.x;
    const int base = b * 1024 + t * 4;
    int s = 0;
#pragma unroll
    for (int j = 0; j < 4; ++j) {
        int idx = base + j;
        if (idx < M) s += in[idx];
    }
#pragma unroll
    for (int off = 32; off >= 1; off >>= 1) s += __shfl_xor(s, off);
    __shared__ int wsum[4];
    if ((t & 63) == 0) wsum[t >> 6] = s;
    __syncthreads();
    if (t == 0) blocksum[b] = wsum[0] + wsum[1] + wsum[2] + wsum[3];
}

__global__ __launch_bounds__(1024)
void scan_g2(int* __restrict__ a, int nb) {
    __shared__ int s[1024];
    const int t = threadIdx.x;
    int v = (t < nb) ? a[t] : 0;
    s[t] = v;
    __syncthreads();
    for (int off = 1; off < 1024; off <<= 1) {
        int x = (t >= off) ? s[t - off] : 0;
        __syncthreads();
        s[t] += x;
        __syncthreads();
    }
    if (t < nb) a[t] = s[t] - v;    // exclusive
}

__global__ __launch_bounds__(256)
void scan_g3(const int* __restrict__ in, const int* __restrict__ blockoff,
             int* __restrict__ out, int M) {
    __shared__ int ssum[256];
    const int b = blockIdx.x, t = threadIdx.x;
    const int base = b * 1024 + t * 4;
    int c[4];
#pragma unroll
    for (int j = 0; j < 4; ++j) {
        int idx = base + j;
        c[j] = (idx < M) ? in[idx] : 0;
    }
    const int tot = c[0] + c[1] + c[2] + c[3];
    ssum[t] = tot;
    __syncthreads();
    for (int off = 1; off < 256; off <<= 1) {
        int v = (t >= off) ? ssum[t - off] : 0;
        __syncthreads();
        ssum[t] += v;
        __syncthreads();
    }
    int run = blockoff[b] + ssum[t] - tot;
#pragma unroll
    for (int j = 0; j < 4; ++j) {
        int idx = base + j;
        if (idx < M) { out[idx] = run; run += c[j]; }
    }
}

// ============================ weight prep: Wt[c][k] = bf16(W[k][c])

__global__ __launch_bounds__(128)
void wt_prep_all(const float* __restrict__ W1, const float* __restrict__ W2,
                 const float* __restrict__ W3, u16* __restrict__ Wt1,
                 u16* __restrict__ Wt2, u16* __restrict__ Wt3) {
    const int b = blockIdx.x, k = threadIdx.x;
    if (b < 128)       Wt1[b * 128 + k] = bf16_bits(W1[k * 128 + b]);
    else if (b < 256)  { int c = b - 128; Wt2[c * 128 + k] = bf16_bits(W2[k * 128 + c]); }
    else               { int c = b - 256; Wt3[c * 128 + k] = bf16_bits(W3[k * 64 + c]); }
}

// ============================ MFMA phases
// A: 64 rows x 128 bf16 in LDS, row stride 136. Wt: [C][128] bf16.
// Layout (HW-verified rounds 6-15): A row=lane&15, k=(lane>>4)*8+j;
// B col=lane&15; D col=lane&15, row=(lane>>4)*4+reg.

// two-plane (hi+lo) version — layer 1 only (raw f32 features)
template <int C>
__device__ __forceinline__
void mfma_store2(const u16* sAh, const u16* sAl, const u16* __restrict__ Wt,
                 u16* __restrict__ H, int row0, int N, int t) {
    constexpr int NT = C / 16;
    const int wid = t >> 6, lane = t & 63;
    const int r0 = wid * 16;
    const int arow = r0 + (lane & 15);
    const int kb = (lane >> 4) * 8;

    f32x4 acc[NT];
#pragma unroll
    for (int i = 0; i < NT; ++i) acc[i] = (f32x4){0.f, 0.f, 0.f, 0.f};

    const u16* wbase = Wt + (size_t)(lane & 15) * 128 + kb;

#pragma unroll
    for (int kk = 0; kk < 4; ++kk) {
        short8 ah = *(const short8*)(&sAh[arow * 136 + kk * 32 + kb]);
        short8 al = *(const short8*)(&sAl[arow * 136 + kk * 32 + kb]);
#pragma unroll
        for (int ct = 0; ct < NT; ++ct) {
            short8 bf = *(const short8*)(wbase + ct * 16 * 128 + kk * 32);
            acc[ct] = __builtin_amdgcn_mfma_f32_16x16x32_bf16(ah, bf, acc[ct], 0, 0, 0);
            acc[ct] = __builtin_amdgcn_mfma_f32_16x16x32_bf16(al, bf, acc[ct], 0, 0, 0);
        }
    }

    const int rbase = row0 + r0 + (lane >> 4) * 4;
#pragma unroll
    for (int ct = 0; ct < NT; ++ct) {
        int gcol = ct * 16 + (lane & 15);
#pragma unroll
        for (int r = 0; r < 4; ++r) {
            int grow = rbase + r;
            if (grow < N) H[(size_t)grow * C + gcol] = bf16_bits(acc[ct][r]);
        }
    }
}

// single-plane version — layers 2-3 (activations already bf16-filtered)
template <int C>
__device__ __forceinline__
void mfma_store1(const u16* sA, const u16* __restrict__ Wt,
                 u16* __restrict__ H, int row0, int N, int t) {
    constexpr int NT = C / 16;
    const int wid = t >> 6, lane = t & 63;
    const int r0 = wid * 16;
    const int arow = r0 + (lane & 15);
    const int kb = (lane >> 4) * 8;

    f32x4 acc[NT];
#pragma unroll
    for (int i = 0; i < NT; ++i) acc[i] = (f32x4){0.f, 0.f, 0.f, 0.f};

    const u16* wbase = Wt + (size_t)(lane & 15) * 128 + kb;

#pragma unroll
    for (int kk = 0; kk < 4; ++kk) {
        short8 a = *(const short8*)(&sA[arow * 136 + kk * 32 + kb]);
#pragma unroll
        for (int ct = 0; ct < NT; ++ct) {
            short8 bf = *(const short8*)(wbase + ct * 16 * 128 + kk * 32);
            acc[ct] = __builtin_amdgcn_mfma_f32_16x16x32_bf16(a, bf, acc[ct], 0, 0, 0);
        }
    }

    const int rbase = row0 + r0 + (lane >> 4) * 4;
#pragma unroll
    for (int ct = 0; ct < NT; ++ct) {
        int gcol = ct * 16 + (lane & 15);
#pragma unroll
        for (int r = 0; r < 4; ++r) {
            int grow = rbase + r;
            if (grow < N) H[(size_t)grow * C + gcol] = bf16_bits(acc[ct][r]);
        }
    }
}

// ============================ fused layer-1 GEMM (absorbs x_prep, hi/lo planes)

__global__ __launch_bounds__(256)
void gemm1_fused(const float* __restrict__ X, const float* __restrict__ iso,
                 const u16* __restrict__ Wt, u16* __restrict__ H, int N) {
    __shared__ u16 sAh[64 * 136];
    __shared__ u16 sAl[64 * 136];
    const int t = threadIdx.x;
    const int row0 = blockIdx.x * 64;

    if (blockIdx.x == 0 && t < 64) ((u32*)H)[(size_t)N * 64 + t] = 0;   // zero pad row

    for (int i = t; i < 2048; i += 256) {       // 64 rows x 32 float4-chunks
        int r = i >> 5, kv = (i & 31) << 2;
        int gr = row0 + r;
        if (gr >= N) gr = N - 1;
        float s = iso[gr];
        float4 x = *(const float4*)(X + (size_t)gr * 128 + kv);
        u16 h0, l0, h1, l1, h2, l2, h3, l3;
        split_hi_lo(x.x * s, h0, l0);
        split_hi_lo(x.y * s, h1, l1);
        split_hi_lo(x.z * s, h2, l2);
        split_hi_lo(x.w * s, h3, l3);
        uint2 hp = make_uint2((u32)h0 | ((u32)h1 << 16), (u32)h2 | ((u32)h3 << 16));
        uint2 lp = make_uint2((u32)l0 | ((u32)l1 << 16), (u32)l2 | ((u32)l3 << 16));
        *(uint2*)(&sAh[r * 136 + kv]) = hp;
        *(uint2*)(&sAl[r * 136 + kv]) = lp;
    }
    __syncthreads();
    mfma_store2<128>(sAh, sAl, Wt, H, row0, N, t);
}

// ============================ layers 2-3 GEMM: single bf16 plane from global

template <int C>
__global__ __launch_bounds__(256)
void gemm_mfma(const u16* __restrict__ A,
               const u16* __restrict__ Wt, u16* __restrict__ H, int N) {
    __shared__ u16 sA[64 * 136];
    const int t = threadIdx.x;
    const int row0 = blockIdx.x * 64;

    if (blockIdx.x == 0 && t < C / 2) ((u32*)H)[(size_t)N * (C / 2) + t] = 0;  // zero pad row

    for (int c = t; c < 1024; c += 256) {       // 64 rows x 16 uint4-chunks
        int r = c >> 4, kc = c & 15;
        int gr = row0 + r;
        if (gr >= N) gr = N - 1;
        *(uint4*)(&sA[r * 136 + kc * 8]) = *(const uint4*)(A + (size_t)gr * 128 + kc * 8);
    }
    __syncthreads();
    mfma_store1<C>(sA, Wt, H, row0, N, t);
}

// ============================ wide gather: 4 rows (edges) per dwordx4 load
// lane l reads bytes (l&15)*16 of row csr[e + 4g + (l>>4)]; acc = 8 cols/lane.
// CSR rows are padded to multiples of 4 with index N (zero row).

__device__ __forceinline__
void gather128w(const u16* __restrict__ Hin, const int* __restrict__ csr,
                int rs, int re, int lane, f32x2* acc) {
    const int sub = lane >> 4;
    const int cb  = (lane & 15) * 8;            // u16 offset within row
    int e = rs;
    while (e < re) {
        int nloc = re - e;
        if (nloc > 64) nloc = 64;               // nloc is a multiple of 4
        int idx = (lane < nloc) ? __builtin_nontemporal_load(&csr[e + lane]) : 0;
        int j = 0;
        for (; j + 16 <= nloc; j += 16) {
            int r0 = __shfl(idx, j + sub);
            int r1 = __shfl(idx, j + 4 + sub);
            int r2 = __shfl(idx, j + 8 + sub);
            int r3 = __shfl(idx, j + 12 + sub);
            uint4 v0 = *(const uint4*)(Hin + (size_t)r0 * 128 + cb);
            uint4 v1 = *(const uint4*)(Hin + (size_t)r1 * 128 + cb);
            uint4 v2 = *(const uint4*)(Hin + (size_t)r2 * 128 + cb);
            uint4 v3 = *(const uint4*)(Hin + (size_t)r3 * 128 + cb);
            pk_acc(acc[0], v0.x); pk_acc(acc[1], v0.y); pk_acc(acc[2], v0.z); pk_acc(acc[3], v0.w);
            pk_acc(acc[0], v1.x); pk_acc(acc[1], v1.y); pk_acc(acc[2], v1.z); pk_acc(acc[3], v1.w);
            pk_acc(acc[0], v2.x); pk_acc(acc[1], v2.y); pk_acc(acc[2], v2.z); pk_acc(acc[3], v2.w);
            pk_acc(acc[0], v3.x); pk_acc(acc[1], v3.y); pk_acc(acc[2], v3.z); pk_acc(acc[3], v3.w);
        }
        for (; j < nloc; j += 4) {
            int r0 = __shfl(idx, j + sub);
            uint4 v0 = *(const uint4*)(Hin + (size_t)r0 * 128 + cb);
            pk_acc(acc[0], v0.x); pk_acc(acc[1], v0.y); pk_acc(acc[2], v0.z); pk_acc(acc[3], v0.w);
        }
        e += nloc;
    }
}

// ============================ aggregation layers 1-2 (one wave per node)
// out = relu(agg*isi + b) * iso  ->  single bf16 plane

__global__ __launch_bounds__(256)
void agg_relu(const u16* __restrict__ H, const int* __restrict__ row_start,
              const int* __restrict__ row_end,
              const int* __restrict__ csr_src, const float* __restrict__ isi,
              const float* __restrict__ iso, const float* __restrict__ bias,
              u16* __restrict__ A, int N) {
    const int wid  = (int)((blockIdx.x * (size_t)blockDim.x + threadIdx.x) >> 6);
    const int lane = threadIdx.x & 63;
    if (wid >= N) return;
    const int rs = row_start[wid];
    const int re = row_end[wid];

    f32x2 acc[4];
#pragma unroll
    for (int i = 0; i < 4; ++i) { acc[i].x = 0.f; acc[i].y = 0.f; }
    gather128w(H, csr_src, rs, re, lane, acc);

    // reduce over the 4 edge-subsets (lanes differing in bits 4,5)
#pragma unroll
    for (int i = 0; i < 4; ++i) {
        acc[i].x += __shfl_xor(acc[i].x, 16); acc[i].y += __shfl_xor(acc[i].y, 16);
        acc[i].x += __shfl_xor(acc[i].x, 32); acc[i].y += __shfl_xor(acc[i].y, 32);
    }

    if (lane < 16) {
        const float sc = isi[wid], so = iso[wid];
        float4 ba = *(const float4*)(bias + lane * 8);
        float4 bb = *(const float4*)(bias + lane * 8 + 4);
        float o[8];
        o[0] = acc[0].x * sc + ba.x; o[1] = acc[0].y * sc + ba.y;
        o[2] = acc[1].x * sc + ba.z; o[3] = acc[1].y * sc + ba.w;
        o[4] = acc[2].x * sc + bb.x; o[5] = acc[2].y * sc + bb.y;
        o[6] = acc[3].x * sc + bb.z; o[7] = acc[3].y * sc + bb.w;
        u32 hp[4];
#pragma unroll
        for (int i = 0; i < 4; ++i) {
            u16 h0 = bf16_bits(fmaxf(o[2 * i], 0.f) * so);
            u16 h1 = bf16_bits(fmaxf(o[2 * i + 1], 0.f) * so);
            hp[i] = (u32)h0 | ((u32)h1 << 16);
        }
        *(uint4*)(A + (size_t)wid * 128 + lane * 8) = *(uint4*)hp;
    }
}

// ============================ final aggregation: 64-col gather + log_softmax
// 4 rows (128 B each) per dwordx2 wave-load: lane covers cols (lane&15)*4..+3.

__global__ __launch_bounds__(256)
void agg_final(const u16* __restrict__ H, const int* __restrict__ row_start,
               const int* __restrict__ row_end,
               const int* __restrict__ csr_src, const float* __restrict__ isi,
               const float* __restrict__ bias, float* __restrict__ Out, int N) {
    const int wid  = (int)((blockIdx.x * (size_t)blockDim.x + threadIdx.x) >> 6);
    const int lane = threadIdx.x & 63;
    if (wid >= N) return;
    const int rs = row_start[wid];
    const int re = row_end[wid];
    const int sub = lane >> 4;
    const int cb  = (lane & 15) * 4;            // u16 offset within 64-col row

    f32x2 a0, a1;
    a0.x = a0.y = a1.x = a1.y = 0.f;
    int e = rs;
    while (e < re) {
        int nloc = re - e;
        if (nloc > 64) nloc = 64;
        int idx = (lane < nloc) ? __builtin_nontemporal_load(&csr_src[e + lane]) : 0;
        int j = 0;
        for (; j + 16 <= nloc; j += 16) {
            int r0 = __shfl(idx, j + sub);
            int r1 = __shfl(idx, j + 4 + sub);
            int r2 = __shfl(idx, j + 8 + sub);
            int r3 = __shfl(idx, j + 12 + sub);
            uint2 v0 = *(const uint2*)(H + (size_t)r0 * 64 + cb);
            uint2 v1 = *(const uint2*)(H + (size_t)r1 * 64 + cb);
            uint2 v2 = *(const uint2*)(H + (size_t)r2 * 64 + cb);
            uint2 v3 = *(const uint2*)(H + (size_t)r3 * 64 + cb);
            pk_acc(a0, v0.x); pk_acc(a1, v0.y);
            pk_acc(a0, v1.x); pk_acc(a1, v1.y);
            pk_acc(a0, v2.x); pk_acc(a1, v2.y);
            pk_acc(a0, v3.x); pk_acc(a1, v3.y);
        }
        for (; j < nloc; j += 4) {
            int r0 = __shfl(idx, j + sub);
            uint2 v0 = *(const uint2*)(H + (size_t)r0 * 64 + cb);
            pk_acc(a0, v0.x); pk_acc(a1, v0.y);
        }
        e += nloc;
    }

    // reduce over 4 edge-subsets
    a0.x += __shfl_xor(a0.x, 16); a0.y += __shfl_xor(a0.y, 16);
    a0.x += __shfl_xor(a0.x, 32); a0.y += __shfl_xor(a0.y, 32);
    a1.x += __shfl_xor(a1.x, 16); a1.y += __shfl_xor(a1.y, 16);
    a1.x += __shfl_xor(a1.x, 32); a1.y += __shfl_xor(a1.y, 32);

    // lanes 0-15 hold cols lane*4..+3; softmax across the 16-lane group
    const float sc = isi[wid];
    float4 b4 = *(const float4*)(bias + (lane & 15) * 4);
    float v0 = a0.x * sc + b4.x;
    float v1 = a0.y * sc + b4.y;
    float v2 = a1.x * sc + b4.z;
    float v3 = a1.y * sc + b4.w;
    float m = fmaxf(fmaxf(v0, v1), fmaxf(v2, v3));
#pragma unroll
    for (int off = 8; off >= 1; off >>= 1) m = fmaxf(m, __shfl_xor(m, off));
    float ss = expf(v0 - m) + expf(v1 - m) + expf(v2 - m) + expf(v3 - m);
#pragma unroll
    for (int off = 8; off >= 1; off >>= 1) ss += __shfl_xor(ss, off);
    float lg = m + logf(ss);
    if (lane < 16) {
        float4 o = make_float4(v0 - lg, v1 - lg, v2 - lg, v3 - lg);
        *(float4*)(Out + (size_t)wid * 64 + lane * 4) = o;
    }
}

// ============================ launch

extern "C" void kernel_launch(void* const* d_in, const int* in_sizes, int n_in,
                              void* d_out, int out_size, void* d_ws, size_t ws_size,
                              hipStream_t stream) {
    const float* features = (const float*)d_in[0];
    const int*   src      = (const int*)d_in[1];
    const int*   dst      = (const int*)d_in[2];
    const float* W1       = (const float*)d_in[3];
    const float* b1       = (const float*)d_in[4];
    const float* W2       = (const float*)d_in[5];
    const float* b2       = (const float*)d_in[6];
    const float* W3       = (const float*)d_in[7];
    const float* b3       = (const float*)d_in[8];
    float*       out      = (float*)d_out;

    const int N  = in_sizes[0] / IN_C;   // 100000
    const int E  = in_sizes[1];          // 1600000
    const int K  = (N + 255) >> 8;       // 391 buckets of 256 nodes
    const int NB = 256;                  // partition blocks
    const int M  = 2 * K * NB;           // concat hist size (dst part | src part)
    const int nbe = (M + 1023) / 1024;

    char* ws = (char*)d_ws;
    const size_t SLOT = 400128;          // >= (N+1)*4, 256B-aligned (1563*256)
    int*   row_end   = (int*)(ws + 1 * SLOT);
    int*   row_start = (int*)(ws + 2 * SLOT);
    float* iso       = (float*)(ws + 3 * SLOT);
    float* isi       = (float*)(ws + 4 * SLOT);
    int*   eblocksum = (int*)(ws + 5 * SLOT);            // <=1024 ints
    int*   csr       = (int*)(ws + 6 * SLOT);            // E + K*768 ints (7.6MB, slot 8MB)
    char*  p         = ws + 6 * SLOT + 8000128;          // 256B-aligned
    // All big-buffer offsets are multiples of 256 B so Hb/Ab rows (256/128 B)
    // never straddle extra cache lines (R14 lesson: 64B-misaligned Hb = +45% FETCH).
    int*   BH        = (int*)p;                          // M ints (800KB)
    int*   OFS       = (int*)(p + 1000448);              // M ints (800KB)
    u32*   pairs     = (u32*)(p + 2000896);              // 2E u32 (12.8MB)
    u16*   Hb        = (u16*)(p + 14801408);             // (N+1)*128 bf16 (25.6MB)
    u16*   Ab        = (u16*)(p + 40401664);             // N*128 bf16 (25.6MB)
    u16*   Wt1       = (u16*)(p + 66001664);             // 128*128 bf16
    u16*   Wt2       = Wt1 + 128 * 128;
    u16*   Wt3       = Wt2 + 128 * 128;                  // 64*128 bf16

    const size_t ldsK2 = (size_t)(2 * K) * sizeof(int);

    // ---- CSR build: dual-key radix partition + fused per-bucket fill ----
    part_hist2<<<NB, 256, ldsK2, stream>>>(src, dst, BH, E, K, NB);
    scan_pass1<<<nbe, 256, 0, stream>>>(BH, eblocksum, M);
    scan_g2<<<1, 1024, 0, stream>>>(eblocksum, nbe);
    scan_g3<<<nbe, 256, 0, stream>>>(BH, eblocksum, OFS, M);
    part_scatter2<<<NB, 256, ldsK2, stream>>>(src, dst, OFS, pairs, E, K, NB);
    bucket_count_src<<<K, 256, 0, stream>>>(pairs, OFS, iso, N, NB, K, E);
    bucket_count_fill<<<K, 256, 0, stream>>>(pairs, OFS, csr, row_start,
                                             row_end, isi, N, NB, K, E);

    // ---- weights ----
    wt_prep_all<<<320, 128, 0, stream>>>(W1, W2, W3, Wt1, Wt2, Wt3);

    // ---- 3-layer GCN ----
    const int gblocks = (N + 63) / 64;
    const int ablocks = (int)(((size_t)N * 64 + 255) / 256);

    gemm1_fused<<<gblocks, 256, 0, stream>>>(features, iso, Wt1, Hb, N);
    agg_relu<<<ablocks, 256, 0, stream>>>(Hb, row_start, row_end, csr, isi, iso, b1, Ab, N);
    gemm_mfma<128><<<gblocks, 256, 0, stream>>>(Ab, Wt2, Hb, N);
    agg_relu<<<ablocks, 256, 0, stream>>>(Hb, row_start, row_end, csr, isi, iso, b2, Ab, N);
    gemm_mfma<64><<<gblocks, 256, 0, stream>>>(Ab, Wt3, Hb, N);
    agg_final<<<ablocks, 256, 0, stream>>>(Hb, row_start, row_end, csr, isi, b3, out, N);
}